// Round 4
// baseline (1147.975 us; speedup 1.0000x reference)
//
#include <hip/hip_runtime.h>
#include <math.h>

typedef unsigned short ushort_t;
typedef unsigned int uint_t;
typedef __attribute__((ext_vector_type(8))) short short8;
typedef __attribute__((ext_vector_type(4))) float f32x4;

#define N_NODES 8192
#define DIM 512
#define KTOT 1024
#define NCOLS 4096
#define BM 128
#define BN 128
#define BK 32
#define NTILE (NCOLS / BN)   // 32 column tiles
#define KIT (KTOT / BK)      // 32 k iterations
#define XRB (N_NODES / BM)   // 64 x rowblocks
#define XTILES (XRB * NTILE) // 2048 x tasks
#define WIMG_USHORTS ((size_t)NTILE * KIT * 8192)
#define MAXLEV_LDS 512

__device__ __forceinline__ float sigm(float x) { return 1.0f / (1.0f + __expf(-x)); }
__device__ __forceinline__ float tanh_fast(float x) {
    float ax = fabsf(x);
    float e = __expf(2.0f * ax);
    float t = 1.0f - 2.0f / (e + 1.0f);
    return copysignf(t, x);
}

// ---------------------------------------------------------------------------
// Prep: weights -> split bf16 (hi+lo) LDS-image layout. (verified r2/r3)
// ---------------------------------------------------------------------------
__global__ void __launch_bounds__(256) prep_wimg_kernel(
    const float* __restrict__ Wx_iou_v, const float* __restrict__ Wh_iou_v,
    const float* __restrict__ Wx_f_v,   const float* __restrict__ Wh_f_v,
    const float* __restrict__ Wx_iou_l, const float* __restrict__ Wh_iou_l,
    const float* __restrict__ Wx_f_l,   const float* __restrict__ Wh_f_l,
    ushort_t* __restrict__ Wimg)
{
    __shared__ float T[32][132];   // T[kk][jloc]
    int p = blockIdx.x >> 5, it = blockIdx.x & 31;
    int tid = threadIdx.x;
#pragma unroll
    for (int e = 0; e < 16; ++e) {
        int lin = e * 256 + tid;
        int dloc = lin & 15, kk = (lin >> 4) & 31, q = lin >> 9;
        int d = p * 16 + dloc;
        int qq = q & 3; bool lang = q >= 4;
        int k = it * 32 + kk;
        const float* W; int col, stride;
        if (qq < 3) { col = qq * DIM + d; stride = 3 * DIM;
            W = (k < DIM) ? (lang ? Wx_iou_l : Wx_iou_v) : (lang ? Wh_iou_l : Wh_iou_v); }
        else        { col = d; stride = DIM;
            W = (k < DIM) ? (lang ? Wx_f_l : Wx_f_v) : (lang ? Wh_f_l : Wh_f_v); }
        int kr = (k < DIM) ? k : (k - DIM);
        T[kk][dloc * 8 + q] = W[(size_t)kr * stride + col];
    }
    __syncthreads();
    size_t tilebase = (size_t)blockIdx.x * 8192;
#pragma unroll
    for (int gch = 0; gch < 4; ++gch) {
        int gi = gch * 256 + tid;
        int plane = gi >> 9, col = (gi >> 2) & 127, gp = gi & 3;
        int gd = gp ^ (col & 3);
        uint_t wds[4];
#pragma unroll
        for (int i = 0; i < 4; ++i) {
            float f0 = T[gd * 8 + 2 * i][col];
            float f1 = T[gd * 8 + 2 * i + 1][col];
            uint_t u0 = __float_as_uint(f0), u1 = __float_as_uint(f1);
            uint_t h0 = u0 & 0xffff0000u, h1 = u1 & 0xffff0000u;
            uint_t v0, v1;
            if (plane == 0) { v0 = h0 >> 16; v1 = h1; }
            else {
                float r0 = f0 - __uint_as_float(h0), r1 = f1 - __uint_as_float(h1);
                v0 = __float_as_uint(r0) >> 16; v1 = __float_as_uint(r1) & 0xffff0000u;
            }
            wds[i] = v1 | v0;
        }
        *(uint4*)(Wimg + tilebase + (size_t)gi * 8) = make_uint4(wds[0], wds[1], wds[2], wds[3]);
    }
}

__global__ void prep_bias_kernel(
    const float* __restrict__ bx_iou_v, const float* __restrict__ bh_iou_v,
    const float* __restrict__ bx_f_v,   const float* __restrict__ bh_f_v,
    const float* __restrict__ bx_iou_l, const float* __restrict__ bh_iou_l,
    const float* __restrict__ bx_f_l,   const float* __restrict__ bh_f_l,
    float* __restrict__ bias)
{
    int j = blockIdx.x * blockDim.x + threadIdx.x;
    if (j >= NCOLS) return;
    int d = j >> 3, q = j & 7;
    int qq = q & 3;
    bool lang = (q & 4) != 0;
    const float* bx; const float* bh; int col;
    if (qq < 3) { col = qq * DIM + d; bx = lang ? bx_iou_l : bx_iou_v; bh = lang ? bh_iou_l : bh_iou_v; }
    else        { col = d;            bx = lang ? bx_f_l  : bx_f_v;   bh = lang ? bh_f_l  : bh_f_v; }
    bias[j] = bx[col] + bh[col];
}

// ---------------------------------------------------------------------------
// Level computation + counting sort + rowblock tables
// ---------------------------------------------------------------------------
__global__ void __launch_bounds__(1024) levels_sort_kernel(
    const int* __restrict__ parent,
    int* __restrict__ order, int* __restrict__ offsets,
    int* __restrict__ counts, int* __restrict__ cursors,
    int* __restrict__ nlev, int* __restrict__ tilestart,
    int* __restrict__ rbStart, int* __restrict__ nodeHrb)
{
    __shared__ int s_level[N_NODES];
    __shared__ int s_assigned;
    __shared__ int s_maxlev;
    int tid = threadIdx.x;
    int pr[8];
#pragma unroll
    for (int ii = 0; ii < 8; ++ii) {
        int i = tid + ii * 1024;
        pr[ii] = parent[i];
        s_level[i] = -1;
    }
    for (int i = tid; i <= N_NODES; i += 1024) counts[i] = 0;
    if (tid == 0) { s_assigned = 0; s_maxlev = 0; }
    __syncthreads();

    for (int pass = 0; pass <= N_NODES; ++pass) {
        int newly = 0;
#pragma unroll
        for (int ii = 0; ii < 8; ++ii) {
            int i = tid + ii * 1024;
            if (s_level[i] < 0) {
                int p = pr[ii];
                if (p == 0) { s_level[i] = 0; newly++; }
                else { int lp = s_level[p - 1]; if (lp >= 0) { s_level[i] = lp + 1; newly++; } }
            }
        }
        if (newly) atomicAdd(&s_assigned, newly);
        __syncthreads();
        int a = s_assigned;
        if (a >= N_NODES) break;
        __syncthreads();
    }

#pragma unroll
    for (int ii = 0; ii < 8; ++ii) {
        int i = tid + ii * 1024;
        int lv = s_level[i];
        atomicAdd(&counts[lv], 1);
        atomicMax(&s_maxlev, lv);
    }
    __syncthreads();
    if (tid == 0) {
        int nl = s_maxlev + 1;
        nlev[0] = nl;
        int off = 0, toff = 0, rb = 0;
        for (int l = 0; l < nl; ++l) {
            offsets[l] = off; cursors[l] = off;
            tilestart[l] = toff; rbStart[l] = rb;
            int mt = (counts[l] + BM - 1) / BM;
            rb += mt;
            toff += mt * NTILE;
            off += counts[l];
        }
        offsets[nl] = off;
        tilestart[nl] = toff;
        rbStart[nl] = rb;
        nlev[1] = toff;   // total h-tiles (== old total tiles)
    }
    __syncthreads();
#pragma unroll
    for (int ii = 0; ii < 8; ++ii) {
        int i = tid + ii * 1024;
        int lv = s_level[i];
        int pos = atomicAdd(&cursors[lv], 1);
        order[pos] = i;
        nodeHrb[i] = rbStart[lv] + ((pos - offsets[lv]) >> 7);
    }
}

// ---------------------------------------------------------------------------
// Staging helpers (verified r2/r3)
// ---------------------------------------------------------------------------
__device__ __forceinline__ void loadA_regs(int it, int tid,
    const int* s_node, const int* s_par,
    const float* __restrict__ inputs, const float* __restrict__ hOut, float* f)
{
    int row = tid >> 1, h16 = tid & 1;
    int node = s_node[row], p = s_par[row];
    bool xside = it < 16;
    bool valid = (node >= 0) && (xside || p > 0);
#pragma unroll
    for (int i = 0; i < 16; ++i) f[i] = 0.f;
    if (valid) {
        const float* base = xside ? (inputs + (size_t)node * DIM + it * 32 + h16 * 16)
                                  : (hOut + (size_t)(p - 1) * DIM + (it - 16) * 32 + h16 * 16);
#pragma unroll
        for (int q4 = 0; q4 < 4; ++q4) {
            float4 v = *(const float4*)(base + q4 * 4);
            f[q4 * 4 + 0] = v.x; f[q4 * 4 + 1] = v.y; f[q4 * 4 + 2] = v.z; f[q4 * 4 + 3] = v.w;
        }
    }
}

__device__ __forceinline__ void loadA_x(int it, int tid, int r0,
    const float* __restrict__ inputs, float* f)
{
    int row = tid >> 1, h16 = tid & 1;
    const float* base = inputs + (size_t)(r0 + row) * DIM + it * 32 + h16 * 16;
#pragma unroll
    for (int q4 = 0; q4 < 4; ++q4) {
        float4 v = *(const float4*)(base + q4 * 4);
        f[q4 * 4 + 0] = v.x; f[q4 * 4 + 1] = v.y; f[q4 * 4 + 2] = v.z; f[q4 * 4 + 3] = v.w;
    }
}

__device__ __forceinline__ void writeA_lds(int tid, ushort_t* Ab, const float* f)
{
    int row = tid >> 1, h16 = tid & 1;
    uint_t hw[8], lw[8];
#pragma unroll
    for (int i = 0; i < 8; ++i) {
        float f0 = f[2 * i], f1 = f[2 * i + 1];
        uint_t u0 = __float_as_uint(f0), u1 = __float_as_uint(f1);
        uint_t h0 = u0 & 0xffff0000u, h1 = u1 & 0xffff0000u;
        float r0 = f0 - __uint_as_float(h0), r1 = f1 - __uint_as_float(h1);
        hw[i] = h1 | (h0 >> 16);
        lw[i] = (__float_as_uint(r1) & 0xffff0000u) | (__float_as_uint(r0) >> 16);
    }
    int gd0 = h16 * 2, gd1 = gd0 + 1, rs = row & 3;
    ushort_t* base = Ab + row * 32;
    *(uint4*)(base + (gd0 ^ rs) * 8)        = make_uint4(hw[0], hw[1], hw[2], hw[3]);
    *(uint4*)(base + (gd1 ^ rs) * 8)        = make_uint4(hw[4], hw[5], hw[6], hw[7]);
    *(uint4*)(base + 4096 + (gd0 ^ rs) * 8) = make_uint4(lw[0], lw[1], lw[2], lw[3]);
    *(uint4*)(base + 4096 + (gd1 ^ rs) * 8) = make_uint4(lw[4], lw[5], lw[6], lw[7]);
}

__device__ __forceinline__ void loadB_regs(int it, int ntile, int tid,
                                           const ushort_t* __restrict__ Wimg, uint4* br)
{
    const uint4* g = (const uint4*)(Wimg + ((size_t)(ntile * KIT + it)) * 8192);
#pragma unroll
    for (int j = 0; j < 4; ++j) br[j] = g[(size_t)tid + 256 * j];
}

__device__ __forceinline__ void writeB_lds(int tid, ushort_t* Bb, const uint4* br)
{
    uint4* d = (uint4*)Bb;
#pragma unroll
    for (int j = 0; j < 4; ++j) d[tid + 256 * j] = br[j];
}

__device__ __forceinline__ void mfma_phase(const ushort_t* Ab, const ushort_t* Bb,
                                           int wr, int wc, int lane, f32x4 acc[4][4])
{
    int l15 = lane & 15, g = lane >> 4;
    short8 ah[4], al[4];
#pragma unroll
    for (int m = 0; m < 4; ++m) {
        int row = wr * 64 + m * 16 + l15;
        const ushort_t* pa = Ab + row * 32 + ((g ^ (row & 3)) * 8);
        ah[m] = *(const short8*)pa;
        al[m] = *(const short8*)(pa + 4096);
    }
#pragma unroll
    for (int n = 0; n < 4; ++n) {
        int col = wc * 64 + n * 16 + l15;
        const ushort_t* pb = Bb + col * 32 + ((g ^ (col & 3)) * 8);
        short8 bh = *(const short8*)pb;
        short8 bl = *(const short8*)(pb + 4096);
#pragma unroll
        for (int m = 0; m < 4; ++m) {
            acc[m][n] = __builtin_amdgcn_mfma_f32_16x16x32_bf16(ah[m], bh, acc[m][n], 0, 0, 0);
            acc[m][n] = __builtin_amdgcn_mfma_f32_16x16x32_bf16(al[m], bh, acc[m][n], 0, 0, 0);
            acc[m][n] = __builtin_amdgcn_mfma_f32_16x16x32_bf16(ah[m], bl, acc[m][n], 0, 0, 0);
        }
    }
}

// ---------------------------------------------------------------------------
// Split dataflow worker: x-tasks (no deps) write preAct; h-tasks (per level)
// do K=512 h-GEMM + epilogue. In-order strided list => deadlock-free.
// ---------------------------------------------------------------------------
__global__ void __launch_bounds__(256, 2) tree_split_kernel(
    const float* __restrict__ inputs, const float* __restrict__ type_mask,
    const ushort_t* __restrict__ Wimg, const float* __restrict__ bias,
    const int* __restrict__ order, const int* __restrict__ offsets,
    const int* __restrict__ nlev, const int* __restrict__ parent,
    const int* __restrict__ rbStart, const int* __restrict__ nodeHrb,
    int* __restrict__ rbCnt, int* __restrict__ xFlag,
    float* __restrict__ preAct, float* __restrict__ out)
{
    float* cOut = out;
    float* hOut = out + (size_t)N_NODES * DIM;

    __shared__ __align__(16) ushort_t sm16[32768];
    __shared__ int s_node[BM];
    __shared__ int s_par[BM];
    __shared__ int s_phrb[BM];
    __shared__ float s_tm[BM][2];
    __shared__ int s_rbs[MAXLEV_LDS];
    __shared__ int s_off[MAXLEV_LDS];

    int tid = threadIdx.x;
    int lane = tid & 63, w = tid >> 6, wr = w >> 1, wc = w & 1;
    int l15 = lane & 15, g = lane >> 4;
    int nl = nlev[0];
    int total = XTILES + nlev[1];

    int nload = nl + 1; if (nload > MAXLEV_LDS) nload = MAXLEV_LDS;
    for (int i = tid; i < nload; i += 256) { s_rbs[i] = rbStart[i]; s_off[i] = offsets[i]; }
    __syncthreads();

    for (int t = blockIdx.x; t < total; t += gridDim.x) {
        if (t < XTILES) {
            // ================= x-task: preAct tile, no dependencies =========
            int ntile = t & (NTILE - 1);
            int xrb = t >> 5;
            int jc = ntile * BN, r0 = xrb * BM;

            f32x4 acc[4][4];
#pragma unroll
            for (int m = 0; m < 4; ++m)
#pragma unroll
                for (int n = 0; n < 4; ++n) acc[m][n] = (f32x4)(0.f);

            {
                float fA[16]; uint4 br[4];
                loadA_x(0, tid, r0, inputs, fA);
                loadB_regs(0, ntile, tid, Wimg, br);
                writeA_lds(tid, sm16, fA);
                writeB_lds(tid, sm16 + 16384, br);
            }
            __syncthreads();
            int cur = 0;
            for (int it = 0; it < 16; ++it) {
                float fA[16]; uint4 br[4];
                bool hn = it < 15;
                if (hn) {
                    loadA_x(it + 1, tid, r0, inputs, fA);
                    loadB_regs(it + 1, ntile, tid, Wimg, br);
                }
                mfma_phase(sm16 + cur * 8192, sm16 + 16384 + cur * 8192, wr, wc, lane, acc);
                if (hn) {
                    writeA_lds(tid, sm16 + (cur ^ 1) * 8192, fA);
                    writeB_lds(tid, sm16 + 16384 + (cur ^ 1) * 8192, br);
                }
                __syncthreads();
                cur ^= 1;
            }

            // direct store to preAct (C/D layout: col=lane&15, row=g*4+reg)
#pragma unroll
            for (int m = 0; m < 4; ++m)
#pragma unroll
                for (int n = 0; n < 4; ++n) {
                    int col = jc + wc * 64 + n * 16 + l15;
                    int rowg = r0 + wr * 64 + m * 16 + g * 4;
#pragma unroll
                    for (int r = 0; r < 4; ++r)
                        preAct[(size_t)(rowg + r) * NCOLS + col] = acc[m][n][r];
                }
            __syncthreads();
            if (tid == 0) {
                __builtin_amdgcn_fence(__ATOMIC_RELEASE, "agent");
                __hip_atomic_store(&xFlag[xrb * NTILE + ntile], 1,
                                   __ATOMIC_RELAXED, __HIP_MEMORY_SCOPE_AGENT);
            }
        } else {
            // ================= h-task: recurrent half ======================
            int t2 = t - XTILES;
            int lev = 0;
            while (lev + 1 < nload && s_rbs[lev + 1] * NTILE <= t2) ++lev;
            int lt = t2 - s_rbs[lev] * NTILE;
            int ntile = lt % NTILE;
            int mt = lt / NTILE;
            int start = s_off[lev];
            int cnt = s_off[lev + 1] - start;
            int jc = ntile * BN;
            int r0 = mt * BM;
            int myhrb = s_rbs[lev] + mt;

            if (tid < BM) {
                int r = r0 + tid;
                int node = (r < cnt) ? order[start + r] : -1;
                s_node[tid] = node;
                int p = (node >= 0) ? parent[node] : 0;
                s_par[tid] = p;
                s_phrb[tid] = (node >= 0 && p > 0) ? nodeHrb[p - 1] : -1;
                float t0 = 0.f, t1 = 0.f;
                if (node >= 0) { t0 = type_mask[node * 2]; t1 = type_mask[node * 2 + 1]; }
                s_tm[tid][0] = t0; s_tm[tid][1] = t1;
            }
            __syncthreads();

            f32x4 acc[4][4];
#pragma unroll
            for (int m = 0; m < 4; ++m)
#pragma unroll
                for (int n = 0; n < 4; ++n) acc[m][n] = (f32x4)(0.f);

            if (lev > 0) {
                // wait for parents' rowblocks (all 32 column tiles done)
                if (tid < BM) {
                    int hrb = s_phrb[tid];
                    if (hrb >= 0) {
                        while (__hip_atomic_load(&rbCnt[hrb], __ATOMIC_RELAXED,
                                                 __HIP_MEMORY_SCOPE_AGENT) < NTILE)
                            __builtin_amdgcn_s_sleep(1);
                    }
                }
                __syncthreads();
                __builtin_amdgcn_fence(__ATOMIC_ACQUIRE, "agent");

                // h-side GEMM: iters 16..31 (K = 512)
                {
                    float fA[16]; uint4 br[4];
                    loadA_regs(16, tid, s_node, s_par, inputs, hOut, fA);
                    loadB_regs(16, ntile, tid, Wimg, br);
                    writeA_lds(tid, sm16, fA);
                    writeB_lds(tid, sm16 + 16384, br);
                }
                __syncthreads();
                int cur = 0;
                for (int it = 16; it < 32; ++it) {
                    float fA[16]; uint4 br[4];
                    bool hn = it < 31;
                    if (hn) {
                        loadA_regs(it + 1, tid, s_node, s_par, inputs, hOut, fA);
                        loadB_regs(it + 1, ntile, tid, Wimg, br);
                    }
                    mfma_phase(sm16 + cur * 8192, sm16 + 16384 + cur * 8192, wr, wc, lane, acc);
                    if (hn) {
                        writeA_lds(tid, sm16 + (cur ^ 1) * 8192, fA);
                        writeB_lds(tid, sm16 + 16384 + (cur ^ 1) * 8192, br);
                    }
                    __syncthreads();
                    cur ^= 1;
                }
            }

            // wait for own preAct column tile
            if (tid < BM) {
                int node = s_node[tid];
                if (node >= 0) {
                    int xi = (node >> 7) * NTILE + ntile;
                    while (__hip_atomic_load(&xFlag[xi], __ATOMIC_RELAXED,
                                             __HIP_MEMORY_SCOPE_AGENT) == 0)
                        __builtin_amdgcn_s_sleep(1);
                }
            }
            __syncthreads();
            __builtin_amdgcn_fence(__ATOMIC_ACQUIRE, "agent");

            // epilogue: acc transpose + preAct + bias + LSTM cell
            float* eps = (float*)sm16;
            int cntloc = cnt - r0; if (cntloc > BM) cntloc = BM;
#pragma unroll
            for (int pass = 0; pass < 2; ++pass) {
                if (wc == pass) {
#pragma unroll
                    for (int m = 0; m < 4; ++m)
#pragma unroll
                        for (int n = 0; n < 4; ++n) {
                            int row = wr * 64 + m * 16 + g * 4;
                            int c = n * 16 + l15;
#pragma unroll
                            for (int r = 0; r < 4; ++r) eps[(row + r) * 68 + c] = acc[m][n][r];
                        }
                }
                __syncthreads();
#pragma unroll
                for (int e = 0; e < 4; ++e) {
                    int task = e * 256 + tid;
                    int row = task >> 3, dl = task & 7;
                    if (row < cntloc) {
                        int node = s_node[row]; int p = s_par[row];
                        const float* ep = &eps[row * 68 + dl * 8];
                        float4 v0 = *(const float4*)ep;
                        float4 v1 = *(const float4*)(ep + 4);
                        int jb = jc + pass * 64 + dl * 8;
                        const float* pa = preAct + (size_t)node * NCOLS + jb;
                        float4 p0 = *(const float4*)pa;
                        float4 p1 = *(const float4*)(pa + 4);
                        float4 b0 = *(const float4*)(bias + jb);
                        float4 b1 = *(const float4*)(bias + jb + 4);
                        int d = jb >> 3;
                        float cp = (p > 0) ? cOut[(size_t)(p - 1) * DIM + d] : 0.f;
                        float cv = sigm(v0.x + p0.x + b0.x) * tanh_fast(v0.z + p0.z + b0.z)
                                 + sigm(v0.w + p0.w + b0.w) * cp;
                        float hv = sigm(v0.y + p0.y + b0.y) * tanh_fast(cv);
                        float cl = sigm(v1.x + p1.x + b1.x) * tanh_fast(v1.z + p1.z + b1.z)
                                 + sigm(v1.w + p1.w + b1.w) * cp;
                        float hl = sigm(v1.y + p1.y + b1.y) * tanh_fast(cl);
                        float tm0 = s_tm[row][0], tm1 = s_tm[row][1];
                        cOut[(size_t)node * DIM + d] = tm0 * cl + tm1 * cv;
                        hOut[(size_t)node * DIM + d] = tm0 * hl + tm1 * hv;
                    }
                }
                __syncthreads();
            }

            if (tid == 0) {
                __builtin_amdgcn_fence(__ATOMIC_RELEASE, "agent");
                __hip_atomic_fetch_add(&rbCnt[myhrb], 1, __ATOMIC_RELAXED,
                                       __HIP_MEMORY_SCOPE_AGENT);
            }
        }
    }
}

// ---------------------------------------------------------------------------
// Fallback (r3, verified): fused 32-iter tiles, per-node counters.
// Used only if ws_size can't hold preAct.
// ---------------------------------------------------------------------------
__global__ void __launch_bounds__(256, 2) tree_dataflow_kernel(
    const float* __restrict__ inputs, const float* __restrict__ type_mask,
    const ushort_t* __restrict__ Wimg, const float* __restrict__ bias,
    const int* __restrict__ order, const int* __restrict__ offsets,
    const int* __restrict__ nlev, const int* __restrict__ parent,
    const int* __restrict__ tilestart, int* __restrict__ readyCnt,
    float* __restrict__ out)
{
    float* cOut = out;
    float* hOut = out + (size_t)N_NODES * DIM;

    __shared__ __align__(16) ushort_t sm16[32768];
    __shared__ int s_node[BM];
    __shared__ int s_par[BM];
    __shared__ float s_tm[BM][2];
    __shared__ int s_ts[MAXLEV_LDS];
    __shared__ int s_off[MAXLEV_LDS];

    int tid = threadIdx.x;
    int lane = tid & 63, w = tid >> 6, wr = w >> 1, wc = w & 1;
    int nl = nlev[0];
    int total = nlev[1];

    int nload = nl + 1; if (nload > MAXLEV_LDS) nload = MAXLEV_LDS;
    for (int i = tid; i < nload; i += 256) { s_ts[i] = tilestart[i]; s_off[i] = offsets[i]; }
    __syncthreads();

    for (int t = blockIdx.x; t < total; t += gridDim.x) {
        int lev = 0;
        while (lev + 1 < nload && s_ts[lev + 1] <= t) ++lev;
        int lt = t - s_ts[lev];
        int ntile = lt % NTILE;
        int mt = lt / NTILE;
        int start = s_off[lev];
        int cnt = s_off[lev + 1] - start;
        int jc = ntile * BN;
        int r0 = mt * BM;

        if (tid < BM) {
            int r = r0 + tid;
            int node = (r < cnt) ? order[start + r] : -1;
            s_node[tid] = node;
            int p = (node >= 0) ? parent[node] : 0;
            s_par[tid] = p;
            float t0 = 0.f, t1 = 0.f;
            if (node >= 0) { t0 = type_mask[node * 2]; t1 = type_mask[node * 2 + 1]; }
            s_tm[tid][0] = t0; s_tm[tid][1] = t1;
        }
        __syncthreads();

        f32x4 acc[4][4];
#pragma unroll
        for (int m = 0; m < 4; ++m)
#pragma unroll
            for (int n = 0; n < 4; ++n) acc[m][n] = (f32x4)(0.f);

        {
            float fA[16]; uint4 br[4];
            loadA_regs(0, tid, s_node, s_par, inputs, hOut, fA);
            loadB_regs(0, ntile, tid, Wimg, br);
            writeA_lds(tid, sm16, fA);
            writeB_lds(tid, sm16 + 16384, br);
        }
        __syncthreads();
        int cur = 0;
        for (int it = 0; it < 16; ++it) {
            float fA[16]; uint4 br[4];
            bool hn = it < 15;
            if (hn) {
                loadA_regs(it + 1, tid, s_node, s_par, inputs, hOut, fA);
                loadB_regs(it + 1, ntile, tid, Wimg, br);
            }
            mfma_phase(sm16 + cur * 8192, sm16 + 16384 + cur * 8192, wr, wc, lane, acc);
            if (hn) {
                writeA_lds(tid, sm16 + (cur ^ 1) * 8192, fA);
                writeB_lds(tid, sm16 + 16384 + (cur ^ 1) * 8192, br);
            }
            __syncthreads();
            cur ^= 1;
        }

        if (tid < BM) {
            int node = s_node[tid], p = s_par[tid];
            if (node >= 0 && p > 0) {
                while (__hip_atomic_load(&readyCnt[p - 1], __ATOMIC_RELAXED,
                                         __HIP_MEMORY_SCOPE_AGENT) < NTILE)
                    __builtin_amdgcn_s_sleep(2);
            }
        }
        __syncthreads();
        if (lev > 0)
            __builtin_amdgcn_fence(__ATOMIC_ACQUIRE, "agent");

        {
            float fA[16]; uint4 br[4];
            loadA_regs(16, tid, s_node, s_par, inputs, hOut, fA);
            loadB_regs(16, ntile, tid, Wimg, br);
            writeA_lds(tid, sm16, fA);
            writeB_lds(tid, sm16 + 16384, br);
        }
        __syncthreads();
        cur = 0;
        for (int it = 16; it < 32; ++it) {
            float fA[16]; uint4 br[4];
            bool hn = it < 31;
            if (hn) {
                loadA_regs(it + 1, tid, s_node, s_par, inputs, hOut, fA);
                loadB_regs(it + 1, ntile, tid, Wimg, br);
            }
            mfma_phase(sm16 + cur * 8192, sm16 + 16384 + cur * 8192, wr, wc, lane, acc);
            if (hn) {
                writeA_lds(tid, sm16 + (cur ^ 1) * 8192, fA);
                writeB_lds(tid, sm16 + 16384 + (cur ^ 1) * 8192, br);
            }
            __syncthreads();
            cur ^= 1;
        }

        float* eps = (float*)sm16;
        int cntloc = cnt - r0; if (cntloc > BM) cntloc = BM;
        int l15 = lane & 15, g = lane >> 4;
#pragma unroll
        for (int pass = 0; pass < 2; ++pass) {
            if (wc == pass) {
#pragma unroll
                for (int m = 0; m < 4; ++m)
#pragma unroll
                    for (int n = 0; n < 4; ++n) {
                        int row = wr * 64 + m * 16 + g * 4;
                        int c = n * 16 + l15;
#pragma unroll
                        for (int r = 0; r < 4; ++r) eps[(row + r) * 68 + c] = acc[m][n][r];
                    }
            }
            __syncthreads();
#pragma unroll
            for (int e = 0; e < 4; ++e) {
                int task = e * 256 + tid;
                int row = task >> 3, dl = task & 7;
                if (row < cntloc) {
                    int node = s_node[row]; int p = s_par[row];
                    const float* ep = &eps[row * 68 + dl * 8];
                    float4 v0 = *(const float4*)ep;
                    float4 v1 = *(const float4*)(ep + 4);
                    int jb = jc + pass * 64 + dl * 8;
                    float4 b0 = *(const float4*)(bias + jb);
                    float4 b1 = *(const float4*)(bias + jb + 4);
                    int d = jb >> 3;
                    float cp = (p > 0) ? cOut[(size_t)(p - 1) * DIM + d] : 0.f;
                    float cv = sigm(v0.x + b0.x) * tanh_fast(v0.z + b0.z) + sigm(v0.w + b0.w) * cp;
                    float hv = sigm(v0.y + b0.y) * tanh_fast(cv);
                    float cl = sigm(v1.x + b1.x) * tanh_fast(v1.z + b1.z) + sigm(v1.w + b1.w) * cp;
                    float hl = sigm(v1.y + b1.y) * tanh_fast(cl);
                    float tm0 = s_tm[row][0], tm1 = s_tm[row][1];
                    cOut[(size_t)node * DIM + d] = tm0 * cl + tm1 * cv;
                    hOut[(size_t)node * DIM + d] = tm0 * hl + tm1 * hv;
                }
            }
            __syncthreads();
        }

        if (tid < BM) {
            int node = s_node[tid];
            if (node >= 0)
                __hip_atomic_fetch_add(&readyCnt[node], 1, __ATOMIC_RELEASE,
                                       __HIP_MEMORY_SCOPE_AGENT);
        }
    }
}

// ---------------------------------------------------------------------------
extern "C" void kernel_launch(void* const* d_in, const int* in_sizes, int n_in,
                              void* d_out, int out_size, void* d_ws, size_t ws_size,
                              hipStream_t stream) {
    const float* inputs      = (const float*)d_in[0];
    const float* type_mask   = (const float*)d_in[1];
    const int*   parent      = (const int*)d_in[2];
    const float* W_ioux_vis  = (const float*)d_in[3];
    const float* b_ioux_vis  = (const float*)d_in[4];
    const float* W_iouh_vis  = (const float*)d_in[5];
    const float* b_iouh_vis  = (const float*)d_in[6];
    const float* W_fx_vis    = (const float*)d_in[7];
    const float* b_fx_vis    = (const float*)d_in[8];
    const float* W_fh_vis    = (const float*)d_in[9];
    const float* b_fh_vis    = (const float*)d_in[10];
    const float* W_ioux_lang = (const float*)d_in[11];
    const float* b_ioux_lang = (const float*)d_in[12];
    const float* W_iouh_lang = (const float*)d_in[13];
    const float* b_iouh_lang = (const float*)d_in[14];
    const float* W_fx_lang   = (const float*)d_in[15];
    const float* b_fx_lang   = (const float*)d_in[16];
    const float* W_fh_lang   = (const float*)d_in[17];
    const float* b_fh_lang   = (const float*)d_in[18];

    ushort_t* Wimg = (ushort_t*)d_ws;                      // 16 MB
    float* bias    = (float*)(Wimg + WIMG_USHORTS);
    int* order     = (int*)(bias + NCOLS);
    int* offsets   = order + N_NODES;
    int* counts    = offsets + (N_NODES + 2);
    int* cursors   = counts + (N_NODES + 2);
    int* nlev      = cursors + (N_NODES + 2);
    int* tilestart = nlev + 8;
    int* rbStart   = tilestart + (N_NODES + 2);
    int* nodeHrb   = rbStart + (N_NODES + 2);
    int* readyCnt  = nodeHrb + N_NODES;
    int* rbCnt     = readyCnt + N_NODES;
    int* xFlag     = rbCnt + 4096;
    size_t paOff = (size_t)((char*)(xFlag + XTILES) - (char*)d_ws);
    paOff = (paOff + 255) & ~(size_t)255;
    float* preAct = (float*)((char*)d_ws + paOff);
    size_t need = paOff + (size_t)N_NODES * NCOLS * sizeof(float);
    bool splitPath = (ws_size >= need);

    float* out = (float*)d_out;

    hipLaunchKernelGGL(prep_wimg_kernel, dim3(NTILE * KIT), dim3(256), 0, stream,
                       W_ioux_vis, W_iouh_vis, W_fx_vis, W_fh_vis,
                       W_ioux_lang, W_iouh_lang, W_fx_lang, W_fh_lang, Wimg);
    hipLaunchKernelGGL(prep_bias_kernel, dim3(NCOLS / 256), dim3(256), 0, stream,
                       b_ioux_vis, b_iouh_vis, b_fx_vis, b_fh_vis,
                       b_ioux_lang, b_iouh_lang, b_fx_lang, b_fh_lang, bias);
    hipLaunchKernelGGL(levels_sort_kernel, dim3(1), dim3(1024), 0, stream,
                       parent, order, offsets, counts, cursors, nlev, tilestart,
                       rbStart, nodeHrb);

    if (splitPath) {
        hipMemsetAsync((void*)rbCnt, 0, (4096 + XTILES) * sizeof(int), stream);
        int occ = 0;
        if (hipOccupancyMaxActiveBlocksPerMultiprocessor(&occ, (const void*)tree_split_kernel, 256, 0) != hipSuccess || occ < 1)
            occ = 1;
        int bpc = occ < 2 ? occ : 2;
        dim3 grid(256 * bpc);
        void* args[] = { (void*)&inputs, (void*)&type_mask, (void*)&Wimg, (void*)&bias,
                         (void*)&order, (void*)&offsets, (void*)&nlev, (void*)&parent,
                         (void*)&rbStart, (void*)&nodeHrb, (void*)&rbCnt, (void*)&xFlag,
                         (void*)&preAct, (void*)&out };
        hipLaunchCooperativeKernel((const void*)tree_split_kernel, grid, dim3(256), args, 0, stream);
    } else {
        hipMemsetAsync((void*)readyCnt, 0, N_NODES * sizeof(int), stream);
        int occ = 0;
        if (hipOccupancyMaxActiveBlocksPerMultiprocessor(&occ, (const void*)tree_dataflow_kernel, 256, 0) != hipSuccess || occ < 1)
            occ = 1;
        int bpc = occ < 2 ? occ : 2;
        dim3 grid(256 * bpc);
        void* args[] = { (void*)&inputs, (void*)&type_mask, (void*)&Wimg, (void*)&bias,
                         (void*)&order, (void*)&offsets, (void*)&nlev, (void*)&parent,
                         (void*)&tilestart, (void*)&readyCnt, (void*)&out };
        hipLaunchCooperativeKernel((const void*)tree_dataflow_kernel, grid, dim3(256), args, 0, stream);
    }
}

// Round 5
// 935.722 us; speedup vs baseline: 1.2268x; 1.2268x over previous
//
#include <hip/hip_runtime.h>
#include <math.h>

typedef unsigned short ushort_t;
typedef unsigned int uint_t;
typedef unsigned long long u64_t;
typedef __attribute__((ext_vector_type(8))) short short8;
typedef __attribute__((ext_vector_type(4))) float f32x4;

#define N_NODES 8192
#define DIM 512
#define KTOT 1024
#define NCOLS 4096
#define BM 128
#define BN 128
#define BK 32
#define NTILE (NCOLS / BN)   // 32 column tiles
#define KIT (KTOT / BK)      // 32 k iterations
#define XRB (N_NODES / BM)   // 64 x rowblocks
#define XTILES (XRB * NTILE) // 2048 x tasks
#define WIMG_USHORTS ((size_t)NTILE * KIT * 8192)
#define MAXLEV_LDS 512

__device__ __forceinline__ float sigm(float x) { return 1.0f / (1.0f + __expf(-x)); }
__device__ __forceinline__ float tanh_fast(float x) {
    float ax = fabsf(x);
    float e = __expf(2.0f * ax);
    float t = 1.0f - 2.0f / (e + 1.0f);
    return copysignf(t, x);
}
// pack fp32 -> (hi bf16 | lo bf16) in one u32 (truncating split, matches GEMM split)
__device__ __forceinline__ uint_t packf(float f) {
    uint_t u = __float_as_uint(f);
    uint_t hi = u & 0xffff0000u;
    float r = f - __uint_as_float(hi);
    return hi | (__float_as_uint(r) >> 16);
}
__device__ __forceinline__ float unpackf(uint_t w) {
    return __uint_as_float(w & 0xffff0000u) + __uint_as_float(w << 16);
}

// ---------------------------------------------------------------------------
// Prep: weights -> split bf16 (hi+lo) LDS-image layout. (verified r2-r4)
// ---------------------------------------------------------------------------
__global__ void __launch_bounds__(256) prep_wimg_kernel(
    const float* __restrict__ Wx_iou_v, const float* __restrict__ Wh_iou_v,
    const float* __restrict__ Wx_f_v,   const float* __restrict__ Wh_f_v,
    const float* __restrict__ Wx_iou_l, const float* __restrict__ Wh_iou_l,
    const float* __restrict__ Wx_f_l,   const float* __restrict__ Wh_f_l,
    ushort_t* __restrict__ Wimg)
{
    __shared__ float T[32][132];   // T[kk][jloc]
    int p = blockIdx.x >> 5, it = blockIdx.x & 31;
    int tid = threadIdx.x;
#pragma unroll
    for (int e = 0; e < 16; ++e) {
        int lin = e * 256 + tid;
        int dloc = lin & 15, kk = (lin >> 4) & 31, q = lin >> 9;
        int d = p * 16 + dloc;
        int qq = q & 3; bool lang = q >= 4;
        int k = it * 32 + kk;
        const float* W; int col, stride;
        if (qq < 3) { col = qq * DIM + d; stride = 3 * DIM;
            W = (k < DIM) ? (lang ? Wx_iou_l : Wx_iou_v) : (lang ? Wh_iou_l : Wh_iou_v); }
        else        { col = d; stride = DIM;
            W = (k < DIM) ? (lang ? Wx_f_l : Wx_f_v) : (lang ? Wh_f_l : Wh_f_v); }
        int kr = (k < DIM) ? k : (k - DIM);
        T[kk][dloc * 8 + q] = W[(size_t)kr * stride + col];
    }
    __syncthreads();
    size_t tilebase = (size_t)blockIdx.x * 8192;
#pragma unroll
    for (int gch = 0; gch < 4; ++gch) {
        int gi = gch * 256 + tid;
        int plane = gi >> 9, col = (gi >> 2) & 127, gp = gi & 3;
        int gd = gp ^ (col & 3);
        uint_t wds[4];
#pragma unroll
        for (int i = 0; i < 4; ++i) {
            float f0 = T[gd * 8 + 2 * i][col];
            float f1 = T[gd * 8 + 2 * i + 1][col];
            uint_t u0 = __float_as_uint(f0), u1 = __float_as_uint(f1);
            uint_t h0 = u0 & 0xffff0000u, h1 = u1 & 0xffff0000u;
            uint_t v0, v1;
            if (plane == 0) { v0 = h0 >> 16; v1 = h1; }
            else {
                float r0 = f0 - __uint_as_float(h0), r1 = f1 - __uint_as_float(h1);
                v0 = __float_as_uint(r0) >> 16; v1 = __float_as_uint(r1) & 0xffff0000u;
            }
            wds[i] = v1 | v0;
        }
        *(uint4*)(Wimg + tilebase + (size_t)gi * 8) = make_uint4(wds[0], wds[1], wds[2], wds[3]);
    }
}

__global__ void prep_bias_kernel(
    const float* __restrict__ bx_iou_v, const float* __restrict__ bh_iou_v,
    const float* __restrict__ bx_f_v,   const float* __restrict__ bh_f_v,
    const float* __restrict__ bx_iou_l, const float* __restrict__ bh_iou_l,
    const float* __restrict__ bx_f_l,   const float* __restrict__ bh_f_l,
    float* __restrict__ bias)
{
    int j = blockIdx.x * blockDim.x + threadIdx.x;
    if (j >= NCOLS) return;
    int d = j >> 3, q = j & 7;
    int qq = q & 3;
    bool lang = (q & 4) != 0;
    const float* bx; const float* bh; int col;
    if (qq < 3) { col = qq * DIM + d; bx = lang ? bx_iou_l : bx_iou_v; bh = lang ? bh_iou_l : bh_iou_v; }
    else        { col = d;            bx = lang ? bx_f_l  : bx_f_v;   bh = lang ? bh_f_l  : bh_f_v; }
    bias[j] = bx[col] + bh[col];
}

// ---------------------------------------------------------------------------
// Level computation + counting sort + rowblock tables (verified r4)
// ---------------------------------------------------------------------------
__global__ void __launch_bounds__(1024) levels_sort_kernel(
    const int* __restrict__ parent,
    int* __restrict__ order, int* __restrict__ offsets,
    int* __restrict__ counts, int* __restrict__ cursors,
    int* __restrict__ nlev, int* __restrict__ tilestart,
    int* __restrict__ rbStart, int* __restrict__ nodeHrb)
{
    __shared__ int s_level[N_NODES];
    __shared__ int s_assigned;
    __shared__ int s_maxlev;
    int tid = threadIdx.x;
    int pr[8];
#pragma unroll
    for (int ii = 0; ii < 8; ++ii) {
        int i = tid + ii * 1024;
        pr[ii] = parent[i];
        s_level[i] = -1;
    }
    for (int i = tid; i <= N_NODES; i += 1024) counts[i] = 0;
    if (tid == 0) { s_assigned = 0; s_maxlev = 0; }
    __syncthreads();

    for (int pass = 0; pass <= N_NODES; ++pass) {
        int newly = 0;
#pragma unroll
        for (int ii = 0; ii < 8; ++ii) {
            int i = tid + ii * 1024;
            if (s_level[i] < 0) {
                int p = pr[ii];
                if (p == 0) { s_level[i] = 0; newly++; }
                else { int lp = s_level[p - 1]; if (lp >= 0) { s_level[i] = lp + 1; newly++; } }
            }
        }
        if (newly) atomicAdd(&s_assigned, newly);
        __syncthreads();
        int a = s_assigned;
        if (a >= N_NODES) break;
        __syncthreads();
    }

#pragma unroll
    for (int ii = 0; ii < 8; ++ii) {
        int i = tid + ii * 1024;
        int lv = s_level[i];
        atomicAdd(&counts[lv], 1);
        atomicMax(&s_maxlev, lv);
    }
    __syncthreads();
    if (tid == 0) {
        int nl = s_maxlev + 1;
        nlev[0] = nl;
        int off = 0, toff = 0, rb = 0;
        for (int l = 0; l < nl; ++l) {
            offsets[l] = off; cursors[l] = off;
            tilestart[l] = toff; rbStart[l] = rb;
            int mt = (counts[l] + BM - 1) / BM;
            rb += mt;
            toff += mt * NTILE;
            off += counts[l];
        }
        offsets[nl] = off;
        tilestart[nl] = toff;
        rbStart[nl] = rb;
        nlev[1] = toff;   // total h-tiles
    }
    __syncthreads();
#pragma unroll
    for (int ii = 0; ii < 8; ++ii) {
        int i = tid + ii * 1024;
        int lv = s_level[i];
        int pos = atomicAdd(&cursors[lv], 1);
        order[pos] = i;
        nodeHrb[i] = rbStart[lv] + ((pos - offsets[lv]) >> 7);
    }
}

// ---------------------------------------------------------------------------
// Staging helpers
// ---------------------------------------------------------------------------
__device__ __forceinline__ void writeA_words(int tid, ushort_t* Ab,
                                             const uint_t* hw, const uint_t* lw)
{
    int row = tid >> 1, h16 = tid & 1;
    int gd0 = h16 * 2, gd1 = gd0 + 1, rs = row & 3;
    ushort_t* base = Ab + row * 32;
    *(uint4*)(base + (gd0 ^ rs) * 8)        = make_uint4(hw[0], hw[1], hw[2], hw[3]);
    *(uint4*)(base + (gd1 ^ rs) * 8)        = make_uint4(hw[4], hw[5], hw[6], hw[7]);
    *(uint4*)(base + 4096 + (gd0 ^ rs) * 8) = make_uint4(lw[0], lw[1], lw[2], lw[3]);
    *(uint4*)(base + 4096 + (gd1 ^ rs) * 8) = make_uint4(lw[4], lw[5], lw[6], lw[7]);
}

__device__ __forceinline__ void writeA_lds(int tid, ushort_t* Ab, const float* f)
{
    uint_t hw[8], lw[8];
#pragma unroll
    for (int i = 0; i < 8; ++i) {
        float f0 = f[2 * i], f1 = f[2 * i + 1];
        uint_t u0 = __float_as_uint(f0), u1 = __float_as_uint(f1);
        uint_t h0 = u0 & 0xffff0000u, h1 = u1 & 0xffff0000u;
        float r0 = f0 - __uint_as_float(h0), r1 = f1 - __uint_as_float(h1);
        hw[i] = h1 | (h0 >> 16);
        lw[i] = (__float_as_uint(r1) & 0xffff0000u) | (__float_as_uint(r0) >> 16);
    }
    writeA_words(tid, Ab, hw, lw);
}

__device__ __forceinline__ void loadA_x(int it, int tid, int r0,
    const float* __restrict__ inputs, float* f)
{
    int row = tid >> 1, h16 = tid & 1;
    const float* base = inputs + (size_t)(r0 + row) * DIM + it * 32 + h16 * 16;
#pragma unroll
    for (int q4 = 0; q4 < 4; ++q4) {
        float4 v = *(const float4*)(base + q4 * 4);
        f[q4 * 4 + 0] = v.x; f[q4 * 4 + 1] = v.y; f[q4 * 4 + 2] = v.z; f[q4 * 4 + 3] = v.w;
    }
}

// h-side A from packed hi|lo u32 rows (plain vector loads; data is final+L3)
__device__ __forceinline__ void loadA_hpack(int it, int tid,
    const int* s_node, const int* s_par,
    const uint_t* __restrict__ hPack, uint_t* hw, uint_t* lw)
{
    int row = tid >> 1, h16 = tid & 1;
    int p = (s_node[row] >= 0) ? s_par[row] : 0;
    uint_t u[16];
    if (p > 0) {
        const uint4* base = (const uint4*)(hPack + (size_t)(p - 1) * DIM + (it - 16) * 32 + h16 * 16);
#pragma unroll
        for (int q4 = 0; q4 < 4; ++q4) {
            uint4 v = base[q4];
            u[q4 * 4] = v.x; u[q4 * 4 + 1] = v.y; u[q4 * 4 + 2] = v.z; u[q4 * 4 + 3] = v.w;
        }
    } else {
#pragma unroll
        for (int i = 0; i < 16; ++i) u[i] = 0;
    }
#pragma unroll
    for (int i = 0; i < 8; ++i) {
        hw[i] = (u[2 * i + 1] & 0xffff0000u) | (u[2 * i] >> 16);
        lw[i] = (u[2 * i + 1] << 16) | (u[2 * i] & 0xffffu);
    }
}

// fallback fp32-gather A load (r3 kernel)
__device__ __forceinline__ void loadA_regs(int it, int tid,
    const int* s_node, const int* s_par,
    const float* __restrict__ inputs, const float* __restrict__ hOut, float* f)
{
    int row = tid >> 1, h16 = tid & 1;
    int node = s_node[row], p = s_par[row];
    bool xside = it < 16;
    bool valid = (node >= 0) && (xside || p > 0);
#pragma unroll
    for (int i = 0; i < 16; ++i) f[i] = 0.f;
    if (valid) {
        const float* base = xside ? (inputs + (size_t)node * DIM + it * 32 + h16 * 16)
                                  : (hOut + (size_t)(p - 1) * DIM + (it - 16) * 32 + h16 * 16);
#pragma unroll
        for (int q4 = 0; q4 < 4; ++q4) {
            float4 v = *(const float4*)(base + q4 * 4);
            f[q4 * 4 + 0] = v.x; f[q4 * 4 + 1] = v.y; f[q4 * 4 + 2] = v.z; f[q4 * 4 + 3] = v.w;
        }
    }
}

__device__ __forceinline__ void loadB_regs(int it, int ntile, int tid,
                                           const ushort_t* __restrict__ Wimg, uint4* br)
{
    const uint4* g = (const uint4*)(Wimg + ((size_t)(ntile * KIT + it)) * 8192);
#pragma unroll
    for (int j = 0; j < 4; ++j) br[j] = g[(size_t)tid + 256 * j];
}

__device__ __forceinline__ void writeB_lds(int tid, ushort_t* Bb, const uint4* br)
{
    uint4* d = (uint4*)Bb;
#pragma unroll
    for (int j = 0; j < 4; ++j) d[tid + 256 * j] = br[j];
}

__device__ __forceinline__ void mfma_phase(const ushort_t* Ab, const ushort_t* Bb,
                                           int wr, int wc, int lane, f32x4 acc[4][4])
{
    int l15 = lane & 15, g = lane >> 4;
    short8 ah[4], al[4];
#pragma unroll
    for (int m = 0; m < 4; ++m) {
        int row = wr * 64 + m * 16 + l15;
        const ushort_t* pa = Ab + row * 32 + ((g ^ (row & 3)) * 8);
        ah[m] = *(const short8*)pa;
        al[m] = *(const short8*)(pa + 4096);
    }
#pragma unroll
    for (int n = 0; n < 4; ++n) {
        int col = wc * 64 + n * 16 + l15;
        const ushort_t* pb = Bb + col * 32 + ((g ^ (col & 3)) * 8);
        short8 bh = *(const short8*)pb;
        short8 bl = *(const short8*)(pb + 4096);
#pragma unroll
        for (int m = 0; m < 4; ++m) {
            acc[m][n] = __builtin_amdgcn_mfma_f32_16x16x32_bf16(ah[m], bh, acc[m][n], 0, 0, 0);
            acc[m][n] = __builtin_amdgcn_mfma_f32_16x16x32_bf16(al[m], bh, acc[m][n], 0, 0, 0);
            acc[m][n] = __builtin_amdgcn_mfma_f32_16x16x32_bf16(ah[m], bl, acc[m][n], 0, 0, 0);
        }
    }
}

// ---------------------------------------------------------------------------
// Fence-free dataflow: all cross-block data goes through the coherence point
// (sc1 atomic stores); flags are relaxed agent atomics; readers use plain
// vector loads post-flag (write-once data => no stale lines possible).
// ---------------------------------------------------------------------------
__global__ void __launch_bounds__(256, 2) tree_split2_kernel(
    const float* __restrict__ inputs, const float* __restrict__ type_mask,
    const ushort_t* __restrict__ Wimg, const float* __restrict__ bias,
    const int* __restrict__ order, const int* __restrict__ offsets,
    const int* __restrict__ nlev, const int* __restrict__ parent,
    const int* __restrict__ rbStart, const int* __restrict__ nodeHrb,
    int* __restrict__ rbCnt, int* __restrict__ xFlag,
    float* __restrict__ preAct, uint_t* __restrict__ hPack, uint_t* __restrict__ cPack,
    float* __restrict__ out)
{
    float* cOut = out;
    float* hOut = out + (size_t)N_NODES * DIM;

    __shared__ __align__(16) ushort_t sm16[32768];
    __shared__ int s_node[BM];
    __shared__ int s_par[BM];
    __shared__ int s_phrb[BM];
    __shared__ float s_tm[BM][2];
    __shared__ int s_rbs[MAXLEV_LDS];
    __shared__ int s_off[MAXLEV_LDS];

    int tid = threadIdx.x;
    int lane = tid & 63, w = tid >> 6, wr = w >> 1, wc = w & 1;
    int l15 = lane & 15, g = lane >> 4;
    int nl = nlev[0];
    int total = XTILES + nlev[1];

    int nload = nl + 1; if (nload > MAXLEV_LDS) nload = MAXLEV_LDS;
    for (int i = tid; i < nload; i += 256) { s_rbs[i] = rbStart[i]; s_off[i] = offsets[i]; }
    __syncthreads();

    for (int t = blockIdx.x; t < total; t += gridDim.x) {
        if (t < XTILES) {
            // ============ x-task: preAct tile (no dependencies) ============
            int ntile = t & (NTILE - 1);
            int xrb = t >> 5;
            int jc = ntile * BN, r0 = xrb * BM;

            f32x4 acc[4][4];
#pragma unroll
            for (int m = 0; m < 4; ++m)
#pragma unroll
                for (int n = 0; n < 4; ++n) acc[m][n] = (f32x4)(0.f);

            {
                float fA[16]; uint4 br[4];
                loadA_x(0, tid, r0, inputs, fA);
                loadB_regs(0, ntile, tid, Wimg, br);
                writeA_lds(tid, sm16, fA);
                writeB_lds(tid, sm16 + 16384, br);
            }
            __syncthreads();
            int cur = 0;
            for (int it = 0; it < 16; ++it) {
                float fA[16]; uint4 br[4];
                bool hn = it < 15;
                if (hn) {
                    loadA_x(it + 1, tid, r0, inputs, fA);
                    loadB_regs(it + 1, ntile, tid, Wimg, br);
                }
                mfma_phase(sm16 + cur * 8192, sm16 + 16384 + cur * 8192, wr, wc, lane, acc);
                if (hn) {
                    writeA_lds(tid, sm16 + (cur ^ 1) * 8192, fA);
                    writeB_lds(tid, sm16 + 16384 + (cur ^ 1) * 8192, br);
                }
                __syncthreads();
                cur ^= 1;
            }

            // transpose acc in LDS, then contiguous 8B sc1 stores to preAct
            float* eps = (float*)sm16;
#pragma unroll
            for (int pass = 0; pass < 2; ++pass) {
                if (wc == pass) {
#pragma unroll
                    for (int m = 0; m < 4; ++m)
#pragma unroll
                        for (int n = 0; n < 4; ++n) {
                            int row = wr * 64 + m * 16 + g * 4;
                            int c = n * 16 + l15;
#pragma unroll
                            for (int r = 0; r < 4; ++r) eps[(row + r) * 68 + c] = acc[m][n][r];
                        }
                }
                __syncthreads();
#pragma unroll
                for (int e = 0; e < 4; ++e) {
                    int task = e * 256 + tid;
                    int row = task >> 3, dl = task & 7;
                    const float* ep = &eps[row * 68 + dl * 8];
                    u64_t* dst = (u64_t*)(preAct + (size_t)(r0 + row) * NCOLS + jc + pass * 64 + dl * 8);
#pragma unroll
                    for (int k2 = 0; k2 < 4; ++k2) {
                        u64_t v = ((u64_t)__float_as_uint(ep[2 * k2 + 1]) << 32)
                                | (u64_t)__float_as_uint(ep[2 * k2]);
                        __hip_atomic_store(dst + k2, v, __ATOMIC_RELAXED, __HIP_MEMORY_SCOPE_AGENT);
                    }
                }
                __syncthreads();
            }

            __builtin_amdgcn_s_waitcnt(0);   // each wave drains its sc1 stores
            __syncthreads();
            if (tid == 0)
                __hip_atomic_store(&xFlag[xrb * NTILE + ntile], 1,
                                   __ATOMIC_RELAXED, __HIP_MEMORY_SCOPE_AGENT);
        } else {
            // ============ h-task: recurrent half ============
            int t2 = t - XTILES;
            int lev = 0;
            while (lev + 1 < nload && s_rbs[lev + 1] * NTILE <= t2) ++lev;
            int lt = t2 - s_rbs[lev] * NTILE;
            int ntile = lt % NTILE;
            int mt = lt / NTILE;
            int start = s_off[lev];
            int cnt = s_off[lev + 1] - start;
            int jc = ntile * BN;
            int r0 = mt * BM;
            int myhrb = s_rbs[lev] + mt;

            if (tid < BM) {
                int r = r0 + tid;
                int node = (r < cnt) ? order[start + r] : -1;
                s_node[tid] = node;
                int p = (node >= 0) ? parent[node] : 0;
                s_par[tid] = p;
                s_phrb[tid] = (node >= 0 && p > 0) ? nodeHrb[p - 1] : -1;
                float t0 = 0.f, t1 = 0.f;
                if (node >= 0) { t0 = type_mask[node * 2]; t1 = type_mask[node * 2 + 1]; }
                s_tm[tid][0] = t0; s_tm[tid][1] = t1;
            }
            __syncthreads();

            f32x4 acc[4][4];
#pragma unroll
            for (int m = 0; m < 4; ++m)
#pragma unroll
                for (int n = 0; n < 4; ++n) acc[m][n] = (f32x4)(0.f);

            if (lev > 0) {
                // wait for parents' rowblocks (flag at coherence point)
                if (tid < BM) {
                    int hrb = s_phrb[tid];
                    if (hrb >= 0) {
                        while (__hip_atomic_load(&rbCnt[hrb], __ATOMIC_RELAXED,
                                                 __HIP_MEMORY_SCOPE_AGENT) < NTILE)
                            __builtin_amdgcn_s_sleep(1);
                    }
                }
                __syncthreads();   // compiler+exec barrier; no cache maintenance

                // h-side GEMM: iters 16..31 (K = 512), packed A staging
                {
                    uint_t hw[8], lw[8]; uint4 br[4];
                    loadA_hpack(16, tid, s_node, s_par, hPack, hw, lw);
                    loadB_regs(16, ntile, tid, Wimg, br);
                    writeA_words(tid, sm16, hw, lw);
                    writeB_lds(tid, sm16 + 16384, br);
                }
                __syncthreads();
                int cur = 0;
                for (int it = 16; it < 32; ++it) {
                    uint_t hw[8], lw[8]; uint4 br[4];
                    bool hn = it < 31;
                    if (hn) {
                        loadA_hpack(it + 1, tid, s_node, s_par, hPack, hw, lw);
                        loadB_regs(it + 1, ntile, tid, Wimg, br);
                    }
                    mfma_phase(sm16 + cur * 8192, sm16 + 16384 + cur * 8192, wr, wc, lane, acc);
                    if (hn) {
                        writeA_words(tid, sm16 + (cur ^ 1) * 8192, hw, lw);
                        writeB_lds(tid, sm16 + 16384 + (cur ^ 1) * 8192, br);
                    }
                    __syncthreads();
                    cur ^= 1;
                }
            }

            // wait for own preAct column tile
            if (tid < BM) {
                int node = s_node[tid];
                if (node >= 0) {
                    int xi = (node >> 7) * NTILE + ntile;
                    while (__hip_atomic_load(&xFlag[xi], __ATOMIC_RELAXED,
                                             __HIP_MEMORY_SCOPE_AGENT) == 0)
                        __builtin_amdgcn_s_sleep(1);
                }
            }
            __syncthreads();

            // epilogue: acc transpose + preAct + bias + LSTM cell
            float* eps = (float*)sm16;
            int cntloc = cnt - r0; if (cntloc > BM) cntloc = BM;
#pragma unroll
            for (int pass = 0; pass < 2; ++pass) {
                if (wc == pass) {
#pragma unroll
                    for (int m = 0; m < 4; ++m)
#pragma unroll
                        for (int n = 0; n < 4; ++n) {
                            int row = wr * 64 + m * 16 + g * 4;
                            int c = n * 16 + l15;
#pragma unroll
                            for (int r = 0; r < 4; ++r) eps[(row + r) * 68 + c] = acc[m][n][r];
                        }
                }
                __syncthreads();
#pragma unroll
                for (int e = 0; e < 4; ++e) {
                    int task = e * 256 + tid;
                    int row = task >> 3, dl = task & 7;
                    if (row < cntloc) {
                        int node = s_node[row]; int p = s_par[row];
                        const float* ep = &eps[row * 68 + dl * 8];
                        float4 v0 = *(const float4*)ep;
                        float4 v1 = *(const float4*)(ep + 4);
                        int jb = jc + pass * 64 + dl * 8;
                        const float* pa = preAct + (size_t)node * NCOLS + jb;
                        float4 p0 = *(const float4*)pa;
                        float4 p1 = *(const float4*)(pa + 4);
                        float4 b0 = *(const float4*)(bias + jb);
                        float4 b1 = *(const float4*)(bias + jb + 4);
                        int d = jb >> 3;
                        float cp = (p > 0) ? unpackf(cPack[(size_t)(p - 1) * DIM + d]) : 0.f;
                        float cv = sigm(v0.x + p0.x + b0.x) * tanh_fast(v0.z + p0.z + b0.z)
                                 + sigm(v0.w + p0.w + b0.w) * cp;
                        float hv = sigm(v0.y + p0.y + b0.y) * tanh_fast(cv);
                        float cl = sigm(v1.x + p1.x + b1.x) * tanh_fast(v1.z + p1.z + b1.z)
                                 + sigm(v1.w + p1.w + b1.w) * cp;
                        float hl = sigm(v1.y + p1.y + b1.y) * tanh_fast(cl);
                        float tm0 = s_tm[row][0], tm1 = s_tm[row][1];
                        float cn = tm0 * cl + tm1 * cv;
                        float hn2 = tm0 * hl + tm1 * hv;
                        size_t oi = (size_t)node * DIM + d;
                        cOut[oi] = cn;                 // d_out: write-only, kernel-end flush
                        hOut[oi] = hn2;
                        __hip_atomic_store(&cPack[oi], packf(cn),
                                           __ATOMIC_RELAXED, __HIP_MEMORY_SCOPE_AGENT);
                        __hip_atomic_store(&hPack[oi], packf(hn2),
                                           __ATOMIC_RELAXED, __HIP_MEMORY_SCOPE_AGENT);
                    }
                }
                __syncthreads();
            }

            __builtin_amdgcn_s_waitcnt(0);   // drain this wave's sc1 stores
            __syncthreads();
            if (tid == 0)
                __hip_atomic_fetch_add(&rbCnt[myhrb], 1, __ATOMIC_RELAXED,
                                       __HIP_MEMORY_SCOPE_AGENT);
        }
    }
}

// ---------------------------------------------------------------------------
// Fallback (r3, verified): fused tiles + fences. Used only if ws too small.
// ---------------------------------------------------------------------------
__global__ void __launch_bounds__(256, 2) tree_dataflow_kernel(
    const float* __restrict__ inputs, const float* __restrict__ type_mask,
    const ushort_t* __restrict__ Wimg, const float* __restrict__ bias,
    const int* __restrict__ order, const int* __restrict__ offsets,
    const int* __restrict__ nlev, const int* __restrict__ parent,
    const int* __restrict__ tilestart, int* __restrict__ readyCnt,
    float* __restrict__ out)
{
    float* cOut = out;
    float* hOut = out + (size_t)N_NODES * DIM;

    __shared__ __align__(16) ushort_t sm16[32768];
    __shared__ int s_node[BM];
    __shared__ int s_par[BM];
    __shared__ float s_tm[BM][2];
    __shared__ int s_ts[MAXLEV_LDS];
    __shared__ int s_off[MAXLEV_LDS];

    int tid = threadIdx.x;
    int lane = tid & 63, w = tid >> 6, wr = w >> 1, wc = w & 1;
    int nl = nlev[0];
    int total = nlev[1];

    int nload = nl + 1; if (nload > MAXLEV_LDS) nload = MAXLEV_LDS;
    for (int i = tid; i < nload; i += 256) { s_ts[i] = tilestart[i]; s_off[i] = offsets[i]; }
    __syncthreads();

    for (int t = blockIdx.x; t < total; t += gridDim.x) {
        int lev = 0;
        while (lev + 1 < nload && s_ts[lev + 1] <= t) ++lev;
        int lt = t - s_ts[lev];
        int ntile = lt % NTILE;
        int mt = lt / NTILE;
        int start = s_off[lev];
        int cnt = s_off[lev + 1] - start;
        int jc = ntile * BN;
        int r0 = mt * BM;

        if (tid < BM) {
            int r = r0 + tid;
            int node = (r < cnt) ? order[start + r] : -1;
            s_node[tid] = node;
            int p = (node >= 0) ? parent[node] : 0;
            s_par[tid] = p;
            float t0 = 0.f, t1 = 0.f;
            if (node >= 0) { t0 = type_mask[node * 2]; t1 = type_mask[node * 2 + 1]; }
            s_tm[tid][0] = t0; s_tm[tid][1] = t1;
        }
        __syncthreads();

        f32x4 acc[4][4];
#pragma unroll
        for (int m = 0; m < 4; ++m)
#pragma unroll
            for (int n = 0; n < 4; ++n) acc[m][n] = (f32x4)(0.f);

        {
            float fA[16]; uint4 br[4];
            loadA_regs(0, tid, s_node, s_par, inputs, hOut, fA);
            loadB_regs(0, ntile, tid, Wimg, br);
            writeA_lds(tid, sm16, fA);
            writeB_lds(tid, sm16 + 16384, br);
        }
        __syncthreads();
        int cur = 0;
        for (int it = 0; it < 16; ++it) {
            float fA[16]; uint4 br[4];
            bool hn = it < 15;
            if (hn) {
                loadA_regs(it + 1, tid, s_node, s_par, inputs, hOut, fA);
                loadB_regs(it + 1, ntile, tid, Wimg, br);
            }
            mfma_phase(sm16 + cur * 8192, sm16 + 16384 + cur * 8192, wr, wc, lane, acc);
            if (hn) {
                writeA_lds(tid, sm16 + (cur ^ 1) * 8192, fA);
                writeB_lds(tid, sm16 + 16384 + (cur ^ 1) * 8192, br);
            }
            __syncthreads();
            cur ^= 1;
        }

        if (tid < BM) {
            int node = s_node[tid], p = s_par[tid];
            if (node >= 0 && p > 0) {
                while (__hip_atomic_load(&readyCnt[p - 1], __ATOMIC_RELAXED,
                                         __HIP_MEMORY_SCOPE_AGENT) < NTILE)
                    __builtin_amdgcn_s_sleep(2);
            }
        }
        __syncthreads();
        if (lev > 0)
            __builtin_amdgcn_fence(__ATOMIC_ACQUIRE, "agent");

        {
            float fA[16]; uint4 br[4];
            loadA_regs(16, tid, s_node, s_par, inputs, hOut, fA);
            loadB_regs(16, ntile, tid, Wimg, br);
            writeA_lds(tid, sm16, fA);
            writeB_lds(tid, sm16 + 16384, br);
        }
        __syncthreads();
        cur = 0;
        for (int it = 16; it < 32; ++it) {
            float fA[16]; uint4 br[4];
            bool hn = it < 31;
            if (hn) {
                loadA_regs(it + 1, tid, s_node, s_par, inputs, hOut, fA);
                loadB_regs(it + 1, ntile, tid, Wimg, br);
            }
            mfma_phase(sm16 + cur * 8192, sm16 + 16384 + cur * 8192, wr, wc, lane, acc);
            if (hn) {
                writeA_lds(tid, sm16 + (cur ^ 1) * 8192, fA);
                writeB_lds(tid, sm16 + 16384 + (cur ^ 1) * 8192, br);
            }
            __syncthreads();
            cur ^= 1;
        }

        float* eps = (float*)sm16;
        int cntloc = cnt - r0; if (cntloc > BM) cntloc = BM;
        int l15 = lane & 15, g = lane >> 4;
#pragma unroll
        for (int pass = 0; pass < 2; ++pass) {
            if (wc == pass) {
#pragma unroll
                for (int m = 0; m < 4; ++m)
#pragma unroll
                    for (int n = 0; n < 4; ++n) {
                        int row = wr * 64 + m * 16 + g * 4;
                        int c = n * 16 + l15;
#pragma unroll
                        for (int r = 0; r < 4; ++r) eps[(row + r) * 68 + c] = acc[m][n][r];
                    }
            }
            __syncthreads();
#pragma unroll
            for (int e = 0; e < 4; ++e) {
                int task = e * 256 + tid;
                int row = task >> 3, dl = task & 7;
                if (row < cntloc) {
                    int node = s_node[row]; int p = s_par[row];
                    const float* ep = &eps[row * 68 + dl * 8];
                    float4 v0 = *(const float4*)ep;
                    float4 v1 = *(const float4*)(ep + 4);
                    int jb = jc + pass * 64 + dl * 8;
                    float4 b0 = *(const float4*)(bias + jb);
                    float4 b1 = *(const float4*)(bias + jb + 4);
                    int d = jb >> 3;
                    float cp = (p > 0) ? cOut[(size_t)(p - 1) * DIM + d] : 0.f;
                    float cv = sigm(v0.x + b0.x) * tanh_fast(v0.z + b0.z) + sigm(v0.w + b0.w) * cp;
                    float hv = sigm(v0.y + b0.y) * tanh_fast(cv);
                    float cl = sigm(v1.x + b1.x) * tanh_fast(v1.z + b1.z) + sigm(v1.w + b1.w) * cp;
                    float hl = sigm(v1.y + b1.y) * tanh_fast(cl);
                    float tm0 = s_tm[row][0], tm1 = s_tm[row][1];
                    cOut[(size_t)node * DIM + d] = tm0 * cl + tm1 * cv;
                    hOut[(size_t)node * DIM + d] = tm0 * hl + tm1 * hv;
                }
            }
            __syncthreads();
        }

        if (tid < BM) {
            int node = s_node[tid];
            if (node >= 0)
                __hip_atomic_fetch_add(&readyCnt[node], 1, __ATOMIC_RELEASE,
                                       __HIP_MEMORY_SCOPE_AGENT);
        }
    }
}

// ---------------------------------------------------------------------------
extern "C" void kernel_launch(void* const* d_in, const int* in_sizes, int n_in,
                              void* d_out, int out_size, void* d_ws, size_t ws_size,
                              hipStream_t stream) {
    const float* inputs      = (const float*)d_in[0];
    const float* type_mask   = (const float*)d_in[1];
    const int*   parent      = (const int*)d_in[2];
    const float* W_ioux_vis  = (const float*)d_in[3];
    const float* b_ioux_vis  = (const float*)d_in[4];
    const float* W_iouh_vis  = (const float*)d_in[5];
    const float* b_iouh_vis  = (const float*)d_in[6];
    const float* W_fx_vis    = (const float*)d_in[7];
    const float* b_fx_vis    = (const float*)d_in[8];
    const float* W_fh_vis    = (const float*)d_in[9];
    const float* b_fh_vis    = (const float*)d_in[10];
    const float* W_ioux_lang = (const float*)d_in[11];
    const float* b_ioux_lang = (const float*)d_in[12];
    const float* W_iouh_lang = (const float*)d_in[13];
    const float* b_iouh_lang = (const float*)d_in[14];
    const float* W_fx_lang   = (const float*)d_in[15];
    const float* b_fx_lang   = (const float*)d_in[16];
    const float* W_fh_lang   = (const float*)d_in[17];
    const float* b_fh_lang   = (const float*)d_in[18];

    ushort_t* Wimg = (ushort_t*)d_ws;                      // 16 MB
    float* bias    = (float*)(Wimg + WIMG_USHORTS);
    int* order     = (int*)(bias + NCOLS);
    int* offsets   = order + N_NODES;
    int* counts    = offsets + (N_NODES + 2);
    int* cursors   = counts + (N_NODES + 2);
    int* nlev      = cursors + (N_NODES + 2);
    int* tilestart = nlev + 8;
    int* rbStart   = tilestart + (N_NODES + 2);
    int* nodeHrb   = rbStart + (N_NODES + 2);
    int* readyCnt  = nodeHrb + N_NODES;
    int* rbCnt     = readyCnt + N_NODES;
    int* xFlag     = rbCnt + 4096;
    size_t off2 = (size_t)((char*)(xFlag + XTILES) - (char*)d_ws);
    off2 = (off2 + 255) & ~(size_t)255;
    uint_t* hPack = (uint_t*)((char*)d_ws + off2);                       // 16 MB
    uint_t* cPack = hPack + (size_t)N_NODES * DIM;                       // 16 MB
    float* preAct = (float*)(cPack + (size_t)N_NODES * DIM);             // 128 MB
    size_t need = off2 + 2 * (size_t)N_NODES * DIM * sizeof(uint_t)
                + (size_t)N_NODES * NCOLS * sizeof(float);
    bool splitPath = (ws_size >= need);

    float* out = (float*)d_out;

    hipLaunchKernelGGL(prep_wimg_kernel, dim3(NTILE * KIT), dim3(256), 0, stream,
                       W_ioux_vis, W_iouh_vis, W_fx_vis, W_fh_vis,
                       W_ioux_lang, W_iouh_lang, W_fx_lang, W_fh_lang, Wimg);
    hipLaunchKernelGGL(prep_bias_kernel, dim3(NCOLS / 256), dim3(256), 0, stream,
                       b_ioux_vis, b_iouh_vis, b_fx_vis, b_fh_vis,
                       b_ioux_lang, b_iouh_lang, b_fx_lang, b_fh_lang, bias);
    hipLaunchKernelGGL(levels_sort_kernel, dim3(1), dim3(1024), 0, stream,
                       parent, order, offsets, counts, cursors, nlev, tilestart,
                       rbStart, nodeHrb);

    if (splitPath) {
        hipMemsetAsync((void*)rbCnt, 0, (4096 + XTILES) * sizeof(int), stream);
        int occ = 0;
        if (hipOccupancyMaxActiveBlocksPerMultiprocessor(&occ, (const void*)tree_split2_kernel, 256, 0) != hipSuccess || occ < 1)
            occ = 1;
        int bpc = occ < 2 ? occ : 2;
        dim3 grid(256 * bpc);
        void* args[] = { (void*)&inputs, (void*)&type_mask, (void*)&Wimg, (void*)&bias,
                         (void*)&order, (void*)&offsets, (void*)&nlev, (void*)&parent,
                         (void*)&rbStart, (void*)&nodeHrb, (void*)&rbCnt, (void*)&xFlag,
                         (void*)&preAct, (void*)&hPack, (void*)&cPack, (void*)&out };
        hipLaunchCooperativeKernel((const void*)tree_split2_kernel, grid, dim3(256), args, 0, stream);
    } else {
        hipMemsetAsync((void*)readyCnt, 0, N_NODES * sizeof(int), stream);
        int occ = 0;
        if (hipOccupancyMaxActiveBlocksPerMultiprocessor(&occ, (const void*)tree_dataflow_kernel, 256, 0) != hipSuccess || occ < 1)
            occ = 1;
        int bpc = occ < 2 ? occ : 2;
        dim3 grid(256 * bpc);
        void* args[] = { (void*)&inputs, (void*)&type_mask, (void*)&Wimg, (void*)&bias,
                         (void*)&order, (void*)&offsets, (void*)&nlev, (void*)&parent,
                         (void*)&tilestart, (void*)&readyCnt, (void*)&out };
        hipLaunchCooperativeKernel((const void*)tree_dataflow_kernel, grid, dim3(256), args, 0, stream);
    }
}